// Round 1
// 162.963 us; speedup vs baseline: 1.0034x; 1.0034x over previous
//
#include <hip/hip_runtime.h>
#include <hip/hip_bf16.h>

#define NV 100000
#define ND 64
#define NB 4096
#define NL 200
#define MT 13        // m-tiles of 16 rows -> 208 (200 real + 8 zero pad)

typedef __bf16 bf16_t;
typedef __bf16 bf16x8 __attribute__((ext_vector_type(8)));
typedef float f32x4 __attribute__((ext_vector_type(4)));

#define TB_ELEMS ((long)NV * ND)   // bf16 shadow table elems (12.8 MB)

// ---- kernel 0: one-shot f32 -> bf16 table conversion (HBM-bound, ~6us) ----
__global__ __launch_bounds__(256)
void cvt_kernel(const float* __restrict__ emb, bf16_t* __restrict__ tb)
{
    long i = ((long)blockIdx.x * 256 + threadIdx.x) * 8;
    if (i < TB_ELEMS) {
        f32x4 a0 = *(const f32x4*)(emb + i);
        f32x4 a1 = *(const f32x4*)(emb + i + 4);
        bf16x8 o;
#pragma unroll
        for (int j = 0; j < 4; ++j) { o[j] = (bf16_t)a0[j]; o[j + 4] = (bf16_t)a1[j]; }
        *(bf16x8*)(tb + i) = o;
    }
}

// LDS layout: histA/wbT are UNPADDED (64 elems/row) with a 16B-granular XOR
// swizzle: elem_offset_in_row ^= (row&7)<<3. Same involution on write & read.
// - gather ds_write_b128: group16 = (i ^ (l&7)) -> conflict-free per 8 lanes
// - A-frag ds_read_b128:  group16 = (quad ^ (col&7)) [+kb bit] -> conflict-free
// - B-frag ds_read_b128:  group16 = ((2kb+quad') ^ (n&7)) -> conflict-free
// - phase5 scalar b16 reads: 2 lanes/bank -> free (m136)
// Total LDS ~38.3 KB -> 4 workgroups/CU (was 43 KB -> 3).
__global__ __launch_bounds__(256)
void din_kernel1(const int* __restrict__ item_ids,
                 const int* __restrict__ history,
                 const int* __restrict__ hist_len,
                 const float* __restrict__ emb,
                 const bf16_t* __restrict__ tb,
                 const float* __restrict__ aW1,
                 const float* __restrict__ ab1,
                 const float* __restrict__ aW2,
                 float* __restrict__ comb_ws)
{
    __shared__ __align__(16) bf16_t histA[208 * 64];
    __shared__ __align__(16) bf16_t wbT[64 * 64];      // transposed: wbT[n][k]
    __shared__ float tgt[64];
    __shared__ float cb[64];
    __shared__ __align__(16) float scores[208];
    __shared__ float wts[208];
    __shared__ float pp[4 * 64];
    __shared__ float red[8];
    __shared__ float pooled[64];

    const int b   = blockIdx.x;
    const int tid = threadIdx.x;
    const int len = hist_len[b];

    // ---- phase 1: target row (f32) + gather history from bf16 table ----
    if (tid < 64) tgt[tid] = emb[(long)item_ids[b] * ND + tid];

    {
        const int p  = tid & 1;       // half of a row: 32 bf16 = 64 B
        const int l0 = tid >> 1;      // rows 0..127
        const int l1 = l0 + 128;      // rows 128..255 (stores clipped at 208)
        const bf16x8 z = (bf16x8)(bf16_t)0.f;
        bf16x8 v00 = z, v01 = z, v02 = z, v03 = z;
        bf16x8 v10 = z, v11 = z, v12 = z, v13 = z;
        // issue ALL loads before any LDS store: up to 8 b128 loads in flight
        if (l0 < len) {
            const bf16_t* s = tb + (long)history[(long)b * NL + l0] * ND + p * 32;
            v00 = *(const bf16x8*)(s);
            v01 = *(const bf16x8*)(s + 8);
            v02 = *(const bf16x8*)(s + 16);
            v03 = *(const bf16x8*)(s + 24);
        }
        if (l1 < len) {               // len <= 200, so this also implies l1 < NL
            const bf16_t* s = tb + (long)history[(long)b * NL + l1] * ND + p * 32;
            v10 = *(const bf16x8*)(s);
            v11 = *(const bf16x8*)(s + 8);
            v12 = *(const bf16x8*)(s + 16);
            v13 = *(const bf16x8*)(s + 24);
        }
        {
            bf16_t* d = &histA[l0 * 64];
            const int S = (l0 & 7) << 3;
            *(bf16x8*)&d[(p * 32 +  0) ^ S] = v00;
            *(bf16x8*)&d[(p * 32 +  8) ^ S] = v01;
            *(bf16x8*)&d[(p * 32 + 16) ^ S] = v02;
            *(bf16x8*)&d[(p * 32 + 24) ^ S] = v03;
        }
        if (l1 < 208) {
            bf16_t* d = &histA[l1 * 64];
            const int S = (l1 & 7) << 3;
            *(bf16x8*)&d[(p * 32 +  0) ^ S] = v10;
            *(bf16x8*)&d[(p * 32 +  8) ^ S] = v11;
            *(bf16x8*)&d[(p * 32 + 16) ^ S] = v12;
            *(bf16x8*)&d[(p * 32 + 24) ^ S] = v13;
        }
    }
    __syncthreads();

    // ---- phase 2: build Wb^T (bf16, swizzled) and c_b ----
    {
        const int n  = tid & 63;
        const int kp = tid >> 6;      // 0..3 -> k = kp*16 + i
        float csum = 0.f;
        bf16x8 w0, w1;
#pragma unroll
        for (int i = 0; i < 16; ++i) {
            int k = kp * 16 + i;                 // wave-uniform
            float tk = tgt[k];                   // LDS broadcast
            float w  = aW1[k * 64 + n] + tk * aW1[(128 + k) * 64 + n];
            if (i < 8) w0[i] = (bf16_t)w; else w1[i - 8] = (bf16_t)w;
            csum += tk * aW1[(64 + k) * 64 + n];
        }
        const int S = (n & 7) << 3;
        *(bf16x8*)&wbT[n * 64 + ((kp * 16    ) ^ S)] = w0;
        *(bf16x8*)&wbT[n * 64 + ((kp * 16 + 8) ^ S)] = w1;
        pp[kp * 64 + n] = csum;
    }
    __syncthreads();
    if (tid < 64) cb[tid] = ab1[tid] + pp[tid] + pp[64 + tid] + pp[128 + tid] + pp[192 + tid];
    __syncthreads();

    // ---- phase 3: H = hist @ Wb via MFMA; relu; dot aW2 -> scores ----
    {
        const int wave = tid >> 6;
        const int lane = tid & 63;
        const int col  = lane & 15;   // = m for A, = n for B, = col for C
        const int quad = lane >> 4;

        bf16x8 bfrag[4][2];
#pragma unroll
        for (int nt = 0; nt < 4; ++nt) {
            const int n = nt * 16 + col;
            const int S = (n & 7) << 3;
#pragma unroll
            for (int kb = 0; kb < 2; ++kb)
                bfrag[nt][kb] = *(const bf16x8*)&wbT[n * 64 + ((kb * 32 + quad * 8) ^ S)];
        }
        float cvals[4], a2vals[4];
#pragma unroll
        for (int nt = 0; nt < 4; ++nt) {
            cvals[nt]  = cb[nt * 16 + col];
            a2vals[nt] = aW2[nt * 16 + col];
        }

        for (int mt = wave; mt < MT; mt += 4) {
            const int row = mt * 16 + col;
            const int S   = (row & 7) << 3;
            const bf16_t* base = &histA[row * 64];
            bf16x8 af0 = *(const bf16x8*)&base[(     quad * 8) ^ S];
            bf16x8 af1 = *(const bf16x8*)&base[(32 + quad * 8) ^ S];
            float sc[4] = {0.f, 0.f, 0.f, 0.f};
#pragma unroll
            for (int nt = 0; nt < 4; ++nt) {
                f32x4 acc = {0.f, 0.f, 0.f, 0.f};
                acc = __builtin_amdgcn_mfma_f32_16x16x32_bf16(af0, bfrag[nt][0], acc, 0, 0, 0);
                acc = __builtin_amdgcn_mfma_f32_16x16x32_bf16(af1, bfrag[nt][1], acc, 0, 0, 0);
#pragma unroll
                for (int i = 0; i < 4; ++i) {
                    float h = acc[i] + cvals[nt];
                    h = h > 0.f ? h : 0.f;
                    sc[i] += h * a2vals[nt];
                }
            }
            // reduce across the 16 cols (low 4 lane bits)
            for (int off = 1; off < 16; off <<= 1)
#pragma unroll
                for (int i = 0; i < 4; ++i)
                    sc[i] += __shfl_xor(sc[i], off, 64);
            if (col == 0) {
                f32x4 outv = {sc[0], sc[1], sc[2], sc[3]};   // rows quad*4+0..3
                *(f32x4*)&scores[mt * 16 + quad * 4] = outv;
            }
        }
    }
    __syncthreads();

    // ---- phase 4: softmax over exactly L=200 ----
    {
        float s = (tid < NL) ? scores[tid] : -1e30f;
        float m = s;
        for (int off = 32; off > 0; off >>= 1) m = fmaxf(m, __shfl_xor(m, off, 64));
        if ((tid & 63) == 0) red[tid >> 6] = m;
        __syncthreads();
        m = fmaxf(fmaxf(red[0], red[1]), fmaxf(red[2], red[3]));
        float e = (tid < NL) ? __expf(s - m) : 0.f;
        float ssum = e;
        for (int off = 32; off > 0; off >>= 1) ssum += __shfl_xor(ssum, off, 64);
        if ((tid & 63) == 0) red[4 + (tid >> 6)] = ssum;
        __syncthreads();
        float tot = red[4] + red[5] + red[6] + red[7];
        if (tid < NL) wts[tid] = e / tot;
    }
    __syncthreads();

    // ---- phase 5: pooled = sum_l w_l * hist_l ----
    {
        const int wave = tid >> 6, lane = tid & 63;
        float acc = 0.f;
        for (int i = 0; i < 50; ++i) {
            int l = wave * 50 + i;
            float wl = wts[l];                       // LDS broadcast
            acc += wl * (float)histA[l * 64 + (lane ^ ((l & 7) << 3))];
        }
        pp[wave * 64 + lane] = acc;
    }
    __syncthreads();
    if (tid < 64) pooled[tid] = pp[tid] + pp[64 + tid] + pp[128 + tid] + pp[192 + tid];
    __syncthreads();

    // ---- phase 6: comb = [tgt, pooled, pooled - tgt] -> ws ----
    if (tid < 192) {
        float v;
        if (tid < 64)       v = tgt[tid];
        else if (tid < 128) v = pooled[tid - 64];
        else                v = pooled[tid - 128] - tgt[tid - 128];
        comb_ws[(long)b * 192 + tid] = v;
    }
}

__global__ __launch_bounds__(256)
void din_kernel2(const float* __restrict__ comb,
                 const float* __restrict__ fW1, const float* __restrict__ fb1,
                 const float* __restrict__ fW2, const float* __restrict__ fb2,
                 const float* __restrict__ fW3, const float* __restrict__ fb3,
                 float* __restrict__ out)
{
    __shared__ float z1s[16 * 130];   // stride 130: breaks 4-way bank conflict
    __shared__ float z2s[16 * 66];
    const int tid = threadIdx.x;
    const int r   = tid >> 4;         // 0..15 rows per block
    const int c   = tid & 15;
    const int row = blockIdx.x * 16 + r;

    // z1[j], j = c*8 + jj
    float acc[8];
    for (int jj = 0; jj < 8; ++jj) acc[jj] = fb1[c * 8 + jj];
    for (int i = 0; i < 192; ++i) {
        float cm = comb[(long)row * 192 + i];
        const float* wr = fW1 + i * 128 + c * 8;
        f32x4 w0 = *(const f32x4*)(wr);
        f32x4 w1 = *(const f32x4*)(wr + 4);
        for (int jj = 0; jj < 4; ++jj) {
            acc[jj]     += cm * w0[jj];
            acc[jj + 4] += cm * w1[jj];
        }
    }
    for (int jj = 0; jj < 8; ++jj) z1s[r * 130 + c * 8 + jj] = fmaxf(acc[jj], 0.f);
    __syncthreads();

    // z2[j], j = c*4 + jj
    float a2[4];
    for (int jj = 0; jj < 4; ++jj) a2[jj] = fb2[c * 4 + jj];
    for (int i = 0; i < 128; ++i) {
        float zv = z1s[r * 130 + i];
        f32x4 w = *(const f32x4*)(fW2 + i * 64 + c * 4);
        for (int jj = 0; jj < 4; ++jj) a2[jj] += zv * w[jj];
    }
    for (int jj = 0; jj < 4; ++jj) z2s[r * 66 + c * 4 + jj] = fmaxf(a2[jj], 0.f);
    __syncthreads();

    if (c == 0) {
        float s = fb3[0];
        for (int j = 0; j < 64; ++j) s += z2s[r * 66 + j] * fW3[j];
        out[row] = 1.f / (1.f + __expf(-s));
    }
}

extern "C" void kernel_launch(void* const* d_in, const int* in_sizes, int n_in,
                              void* d_out, int out_size, void* d_ws, size_t ws_size,
                              hipStream_t stream) {
    const int*   item_ids = (const int*)d_in[0];
    const int*   history  = (const int*)d_in[1];
    const int*   hist_len = (const int*)d_in[2];
    const float* emb      = (const float*)d_in[3];
    const float* aW1      = (const float*)d_in[4];
    const float* ab1      = (const float*)d_in[5];
    const float* aW2      = (const float*)d_in[6];
    // d_in[7] = ab2: softmax is shift-invariant, exactly cancels -> unused
    const float* fW1      = (const float*)d_in[8];
    const float* fb1      = (const float*)d_in[9];
    const float* fW2      = (const float*)d_in[10];
    const float* fb2      = (const float*)d_in[11];
    const float* fW3      = (const float*)d_in[12];
    const float* fb3      = (const float*)d_in[13];

    // ws layout: [0, 12.8MB) bf16 emb table | [12.8MB, +3.1MB) comb
    bf16_t* tb   = (bf16_t*)d_ws;
    float*  comb = (float*)((char*)d_ws + (size_t)(TB_ELEMS * 2));

    cvt_kernel<<<(int)(TB_ELEMS / 8 / 256 + 1), 256, 0, stream>>>(emb, tb);
    din_kernel1<<<NB, 256, 0, stream>>>(item_ids, history, hist_len, emb, tb,
                                        aW1, ab1, aW2, comb);
    din_kernel2<<<NB / 16, 256, 0, stream>>>(comb, fW1, fb1, fW2, fb2, fW3, fb3,
                                             (float*)d_out);
}

// Round 2
// 149.782 us; speedup vs baseline: 1.0917x; 1.0880x over previous
//
#include <hip/hip_runtime.h>
#include <hip/hip_bf16.h>

#define NV 100000
#define ND 64
#define NB 4096
#define NL 200
#define MT 13        // m-tiles of 16 rows -> 208 (200 real + 8 zero pad)

typedef __bf16 bf16_t;
typedef __bf16 bf16x8 __attribute__((ext_vector_type(8)));
typedef float f32x4 __attribute__((ext_vector_type(4)));

#define TB_ELEMS ((long)NV * ND)   // bf16 shadow table elems (12.8 MB)

// ---- kernel 0: one-shot f32 -> bf16 table conversion (HBM-bound, ~6us) ----
__global__ __launch_bounds__(256)
void cvt_kernel(const float* __restrict__ emb, bf16_t* __restrict__ tb)
{
    long i = ((long)blockIdx.x * 256 + threadIdx.x) * 8;
    if (i < TB_ELEMS) {
        f32x4 a0 = *(const f32x4*)(emb + i);
        f32x4 a1 = *(const f32x4*)(emb + i + 4);
        bf16x8 o;
#pragma unroll
        for (int j = 0; j < 4; ++j) { o[j] = (bf16_t)a0[j]; o[j + 4] = (bf16_t)a1[j]; }
        *(bf16x8*)(tb + i) = o;
    }
}

// Fused DIN: gather + attention + softmax + pool + full 3-layer MLP head.
// LDS: histA/wbT unpadded with 16B-granular XOR swizzle (elem ^= (row&7)<<3).
// MLP scratch aliases wbT (dead after phase 3); comb aliases scores (dead
// after phase 4). Total 38304 B -> 4 workgroups/CU.
__global__ __launch_bounds__(256, 4)
void din_kernel1(const int* __restrict__ item_ids,
                 const int* __restrict__ history,
                 const int* __restrict__ hist_len,
                 const float* __restrict__ emb,
                 const bf16_t* __restrict__ tb,
                 const float* __restrict__ aW1,
                 const float* __restrict__ ab1,
                 const float* __restrict__ aW2,
                 const float* __restrict__ fW1, const float* __restrict__ fb1,
                 const float* __restrict__ fW2, const float* __restrict__ fb2,
                 const float* __restrict__ fW3, const float* __restrict__ fb3,
                 float* __restrict__ out)
{
    __shared__ __align__(16) bf16_t histA[208 * 64];
    __shared__ __align__(16) bf16_t wbT[64 * 64];      // transposed: wbT[n][k]
    __shared__ float tgt[64];
    __shared__ float cb[64];
    __shared__ __align__(16) float scores[208];
    __shared__ float wts[208];
    __shared__ float pp[4 * 64];
    __shared__ float red[8];
    __shared__ float pooled[64];

    // aliases (regions dead by the time these are used; barriers in between)
    float* mlp_pp = (float*)wbT;            // 8 KB region: pp8[8*128] / ppB[16*64]
    float* z1     = (float*)wbT + 1024;     // 128 floats
    float* z2     = (float*)wbT + 1152;     // 64 floats
    float* comb_l = scores;                 // 192 floats (<= 208)

    const int b   = blockIdx.x;
    const int tid = threadIdx.x;
    const int len = hist_len[b];

    // ---- phase 1: target row (f32) + gather history from bf16 table ----
    if (tid < 64) tgt[tid] = emb[(long)item_ids[b] * ND + tid];

    {
        const int p  = tid & 1;       // half of a row: 32 bf16 = 64 B
        const int l0 = tid >> 1;      // rows 0..127
        const int l1 = l0 + 128;      // rows 128..255 (stores clipped at 208)
        const bf16x8 z = (bf16x8)(bf16_t)0.f;
        bf16x8 v00 = z, v01 = z, v02 = z, v03 = z;
        bf16x8 v10 = z, v11 = z, v12 = z, v13 = z;
        // issue ALL loads before any LDS store: up to 8 b128 loads in flight
        if (l0 < len) {
            const bf16_t* s = tb + (long)history[(long)b * NL + l0] * ND + p * 32;
            v00 = *(const bf16x8*)(s);
            v01 = *(const bf16x8*)(s + 8);
            v02 = *(const bf16x8*)(s + 16);
            v03 = *(const bf16x8*)(s + 24);
        }
        if (l1 < len) {               // len <= 200, so this also implies l1 < NL
            const bf16_t* s = tb + (long)history[(long)b * NL + l1] * ND + p * 32;
            v10 = *(const bf16x8*)(s);
            v11 = *(const bf16x8*)(s + 8);
            v12 = *(const bf16x8*)(s + 16);
            v13 = *(const bf16x8*)(s + 24);
        }
        {
            bf16_t* d = &histA[l0 * 64];
            const int S = (l0 & 7) << 3;
            *(bf16x8*)&d[(p * 32 +  0) ^ S] = v00;
            *(bf16x8*)&d[(p * 32 +  8) ^ S] = v01;
            *(bf16x8*)&d[(p * 32 + 16) ^ S] = v02;
            *(bf16x8*)&d[(p * 32 + 24) ^ S] = v03;
        }
        if (l1 < 208) {
            bf16_t* d = &histA[l1 * 64];
            const int S = (l1 & 7) << 3;
            *(bf16x8*)&d[(p * 32 +  0) ^ S] = v10;
            *(bf16x8*)&d[(p * 32 +  8) ^ S] = v11;
            *(bf16x8*)&d[(p * 32 + 16) ^ S] = v12;
            *(bf16x8*)&d[(p * 32 + 24) ^ S] = v13;
        }
    }

    // ---- phase 2: build Wb^T (bf16, swizzled) and c_b ----
    // tk read straight from emb (wave-uniform broadcast) -> no barrier needed
    // before this phase; its aW1 loads overlap the gather's latency chains.
    {
        const int n    = tid & 63;
        const int kp   = tid >> 6;    // 0..3 -> k = kp*16 + i (wave id)
        const long trow = (long)item_ids[b] * ND;
        float csum = 0.f;
        bf16x8 w0, w1;
#pragma unroll
        for (int i = 0; i < 16; ++i) {
            int k = kp * 16 + i;                 // wave-uniform
            float tk = emb[trow + k];            // same-addr across lanes
            float w  = aW1[k * 64 + n] + tk * aW1[(128 + k) * 64 + n];
            if (i < 8) w0[i] = (bf16_t)w; else w1[i - 8] = (bf16_t)w;
            csum += tk * aW1[(64 + k) * 64 + n];
        }
        const int S = (n & 7) << 3;
        *(bf16x8*)&wbT[n * 64 + ((kp * 16    ) ^ S)] = w0;
        *(bf16x8*)&wbT[n * 64 + ((kp * 16 + 8) ^ S)] = w1;
        pp[kp * 64 + n] = csum;
    }
    __syncthreads();
    if (tid < 64) cb[tid] = ab1[tid] + pp[tid] + pp[64 + tid] + pp[128 + tid] + pp[192 + tid];
    __syncthreads();

    // ---- phase 3: H = hist @ Wb via MFMA; relu; dot aW2 -> scores ----
    {
        const int wave = tid >> 6;
        const int lane = tid & 63;
        const int col  = lane & 15;   // = m for A, = n for B, = col for C
        const int quad = lane >> 4;

        bf16x8 bfrag[4][2];
#pragma unroll
        for (int nt = 0; nt < 4; ++nt) {
            const int n = nt * 16 + col;
            const int S = (n & 7) << 3;
#pragma unroll
            for (int kb = 0; kb < 2; ++kb)
                bfrag[nt][kb] = *(const bf16x8*)&wbT[n * 64 + ((kb * 32 + quad * 8) ^ S)];
        }
        float cvals[4], a2vals[4];
#pragma unroll
        for (int nt = 0; nt < 4; ++nt) {
            cvals[nt]  = cb[nt * 16 + col];
            a2vals[nt] = aW2[nt * 16 + col];
        }

        for (int mt = wave; mt < MT; mt += 4) {
            const int row = mt * 16 + col;
            const int S   = (row & 7) << 3;
            const bf16_t* base = &histA[row * 64];
            bf16x8 af0 = *(const bf16x8*)&base[(     quad * 8) ^ S];
            bf16x8 af1 = *(const bf16x8*)&base[(32 + quad * 8) ^ S];
            float sc[4] = {0.f, 0.f, 0.f, 0.f};
#pragma unroll
            for (int nt = 0; nt < 4; ++nt) {
                f32x4 acc = {0.f, 0.f, 0.f, 0.f};
                acc = __builtin_amdgcn_mfma_f32_16x16x32_bf16(af0, bfrag[nt][0], acc, 0, 0, 0);
                acc = __builtin_amdgcn_mfma_f32_16x16x32_bf16(af1, bfrag[nt][1], acc, 0, 0, 0);
#pragma unroll
                for (int i = 0; i < 4; ++i) {
                    float h = acc[i] + cvals[nt];
                    h = h > 0.f ? h : 0.f;
                    sc[i] += h * a2vals[nt];
                }
            }
            // reduce across the 16 cols (low 4 lane bits)
            for (int off = 1; off < 16; off <<= 1)
#pragma unroll
                for (int i = 0; i < 4; ++i)
                    sc[i] += __shfl_xor(sc[i], off, 64);
            if (col == 0) {
                f32x4 outv = {sc[0], sc[1], sc[2], sc[3]};   // rows quad*4+0..3
                *(f32x4*)&scores[mt * 16 + quad * 4] = outv;
            }
        }
    }
    __syncthreads();

    // ---- phase 4: softmax over exactly L=200 ----
    {
        float s = (tid < NL) ? scores[tid] : -1e30f;
        float m = s;
        for (int off = 32; off > 0; off >>= 1) m = fmaxf(m, __shfl_xor(m, off, 64));
        if ((tid & 63) == 0) red[tid >> 6] = m;
        __syncthreads();
        m = fmaxf(fmaxf(red[0], red[1]), fmaxf(red[2], red[3]));
        float e = (tid < NL) ? __expf(s - m) : 0.f;
        float ssum = e;
        for (int off = 32; off > 0; off >>= 1) ssum += __shfl_xor(ssum, off, 64);
        if ((tid & 63) == 0) red[4 + (tid >> 6)] = ssum;
        __syncthreads();
        float tot = red[4] + red[5] + red[6] + red[7];
        if (tid < NL) wts[tid] = e / tot;
    }
    __syncthreads();

    // ---- phase 5: pooled = sum_l w_l * hist_l ----
    {
        const int wave = tid >> 6, lane = tid & 63;
        float acc = 0.f;
        for (int i = 0; i < 50; ++i) {
            int l = wave * 50 + i;
            float wl = wts[l];                       // LDS broadcast
            acc += wl * (float)histA[l * 64 + (lane ^ ((l & 7) << 3))];
        }
        pp[wave * 64 + lane] = acc;
    }
    __syncthreads();
    if (tid < 64) pooled[tid] = pp[tid] + pp[64 + tid] + pp[128 + tid] + pp[192 + tid];
    __syncthreads();

    // ---- phase 6: comb = [tgt, pooled, pooled - tgt] -> LDS ----
    if (tid < 192) {
        float v;
        if (tid < 64)       v = tgt[tid];
        else if (tid < 128) v = pooled[tid - 64];
        else                v = pooled[tid - 128] - tgt[tid - 128];
        comb_l[tid] = v;
    }
    __syncthreads();

    // ---- phase 7: z1 = relu(comb @ fW1 + fb1)   [192 -> 128] ----
    {
        const int c = tid & 31;       // output quad: j = c*4 + jj
        const int g = tid >> 5;       // 0..7, i in [g*24, g*24+24)
        f32x4 acc = {0.f, 0.f, 0.f, 0.f};
#pragma unroll
        for (int ii = 0; ii < 24; ++ii) {
            int i = g * 24 + ii;
            float cm = comb_l[i];                       // LDS broadcast
            f32x4 w = *(const f32x4*)(fW1 + (long)i * 128 + c * 4);
#pragma unroll
            for (int jj = 0; jj < 4; ++jj) acc[jj] += cm * w[jj];
        }
        *(f32x4*)&mlp_pp[g * 128 + c * 4] = acc;
    }
    __syncthreads();
    if (tid < 128) {
        float s = fb1[tid];
#pragma unroll
        for (int g = 0; g < 8; ++g) s += mlp_pp[g * 128 + tid];
        z1[tid] = fmaxf(s, 0.f);
    }
    __syncthreads();

    // ---- phase 8: z2 = relu(z1 @ fW2 + fb2)   [128 -> 64] ----
    {
        const int c = tid & 15;       // j = c*4 + jj
        const int g = tid >> 4;       // 0..15, i in [g*8, g*8+8)
        f32x4 acc = {0.f, 0.f, 0.f, 0.f};
#pragma unroll
        for (int ii = 0; ii < 8; ++ii) {
            int i = g * 8 + ii;
            float zv = z1[i];                           // LDS broadcast
            f32x4 w = *(const f32x4*)(fW2 + (long)i * 64 + c * 4);
#pragma unroll
            for (int jj = 0; jj < 4; ++jj) acc[jj] += zv * w[jj];
        }
        *(f32x4*)&mlp_pp[g * 64 + c * 4] = acc;         // reuse (pp8 dead)
    }
    __syncthreads();
    if (tid < 64) {
        float s = fb2[tid];
#pragma unroll
        for (int g = 0; g < 16; ++g) s += mlp_pp[g * 64 + tid];
        z2[tid] = fmaxf(s, 0.f);
    }
    __syncthreads();

    // ---- phase 9: out = sigmoid(z2 . fW3 + fb3) ----
    if (tid < 64) {
        float s = z2[tid] * fW3[tid];
        for (int off = 32; off > 0; off >>= 1) s += __shfl_xor(s, off, 64);
        if (tid == 0) out[b] = 1.f / (1.f + __expf(-(s + fb3[0])));
    }
}

extern "C" void kernel_launch(void* const* d_in, const int* in_sizes, int n_in,
                              void* d_out, int out_size, void* d_ws, size_t ws_size,
                              hipStream_t stream) {
    const int*   item_ids = (const int*)d_in[0];
    const int*   history  = (const int*)d_in[1];
    const int*   hist_len = (const int*)d_in[2];
    const float* emb      = (const float*)d_in[3];
    const float* aW1      = (const float*)d_in[4];
    const float* ab1      = (const float*)d_in[5];
    const float* aW2      = (const float*)d_in[6];
    // d_in[7] = ab2: softmax is shift-invariant, exactly cancels -> unused
    const float* fW1      = (const float*)d_in[8];
    const float* fb1      = (const float*)d_in[9];
    const float* fW2      = (const float*)d_in[10];
    const float* fb2      = (const float*)d_in[11];
    const float* fW3      = (const float*)d_in[12];
    const float* fb3      = (const float*)d_in[13];

    // ws layout: [0, 12.8MB) bf16 emb table
    bf16_t* tb = (bf16_t*)d_ws;

    cvt_kernel<<<(int)(TB_ELEMS / 8 / 256 + 1), 256, 0, stream>>>(emb, tb);
    din_kernel1<<<NB, 256, 0, stream>>>(item_ids, history, hist_len, emb, tb,
                                        aW1, ab1, aW2,
                                        fW1, fb1, fW2, fb2, fW3, fb3,
                                        (float*)d_out);
}

// Round 3
// 149.105 us; speedup vs baseline: 1.0967x; 1.0045x over previous
//
#include <hip/hip_runtime.h>
#include <hip/hip_bf16.h>

#define NV 100000
#define ND 64
#define NB 4096
#define NL 200
#define MT 13        // m-tiles of 16 rows -> 208 (200 real + 8 zero pad)

typedef __bf16 bf16_t;
typedef __bf16 bf16x8 __attribute__((ext_vector_type(8)));
typedef float f32x4 __attribute__((ext_vector_type(4)));

#define TB_ELEMS ((long)NV * ND)      // bf16 shadow emb table elems (12.8 MB)
#define FW1_ELEMS (192 * 128)         // 24576
#define FW2_ELEMS (128 * 64)          // 8192
#define CVT_TOTAL (TB_ELEMS + FW1_ELEMS + FW2_ELEMS)

// ---- kernel 0: f32 -> bf16 conversion: emb table + fW1 + fW2 ----
__global__ __launch_bounds__(256)
void cvt_kernel(const float* __restrict__ emb,
                const float* __restrict__ fW1,
                const float* __restrict__ fW2,
                bf16_t* __restrict__ tb)
{
    long i = ((long)blockIdx.x * 256 + threadIdx.x) * 8;
    if (i >= CVT_TOTAL) return;
    const float* src;
    if (i < TB_ELEMS)                  src = emb + i;
    else if (i < TB_ELEMS + FW1_ELEMS) src = fW1 + (i - TB_ELEMS);
    else                               src = fW2 + (i - TB_ELEMS - FW1_ELEMS);
    f32x4 a0 = *(const f32x4*)(src);
    f32x4 a1 = *(const f32x4*)(src + 4);
    bf16x8 o;
#pragma unroll
    for (int j = 0; j < 4; ++j) { o[j] = (bf16_t)a0[j]; o[j + 4] = (bf16_t)a1[j]; }
    *(bf16x8*)(tb + i) = o;
}

// Fused DIN, 2 batch rows per block (512 threads): all weight loads (aW1,
// fW1, fW2) are issued once per block and applied to both rows.
// histA/wbT: 16B-granular XOR swizzle (elem ^= (row&7)<<3), both sides.
// LDS 77632 B -> 2 blocks/CU (16 waves/CU). MLP scratch aliases histA.
__global__ __launch_bounds__(512, 4)
void din_kernel1(const int* __restrict__ item_ids,
                 const int* __restrict__ history,
                 const int* __restrict__ hist_len,
                 const float* __restrict__ emb,
                 const bf16_t* __restrict__ tb,
                 const float* __restrict__ aW1,
                 const float* __restrict__ ab1,
                 const float* __restrict__ aW2,
                 const bf16_t* __restrict__ fW1b, const float* __restrict__ fb1,
                 const bf16_t* __restrict__ fW2b, const float* __restrict__ fb2,
                 const float* __restrict__ fW3, const float* __restrict__ fb3,
                 float* __restrict__ out)
{
    __shared__ __align__(16) bf16_t histA[2][208 * 64];   // 53248 B
    __shared__ __align__(16) bf16_t wbT[2][64 * 64];      // 16384 B, wbT[n][k]
    __shared__ float tgt[2][64];
    __shared__ __align__(16) float scores[2][208];        // later: comb alias
    __shared__ float wts[2][208];                         // unnormalized e
    __shared__ float pp2[2][512];                         // csum / pool partials
    __shared__ float red[2][8];

    // MLP scratch aliases histA (dead after pooling phase)
    float* pp7 = (float*)histA;              // 8192 floats (32 KB)
    float* z1  = (float*)histA + 8192;       // 2*128
    float* z2  = (float*)histA + 8448;       // 2*64

    const int b0  = blockIdx.x * 2;
    const int tid = threadIdx.x;
    const int len0 = hist_len[b0];
    const int len1 = hist_len[b0 + 1];

    if (tid < 128) {
        int bx = tid >> 6, d = tid & 63;
        tgt[bx][d] = emb[(long)item_ids[b0 + bx] * ND + d];
    }

    // ---- phase 1: gather 2x208 rows from bf16 table (all loads first) ----
    {
        const int p = tid & 1;        // half-row: 32 bf16 = 64 B
        const int s = tid >> 1;       // 0..255
        // slot A: s -> (bxA, lA); slot B: s+256 -> (1, s+48), valid s<160
        const int bxA = (s >= 208);
        const int lA  = s - bxA * 208;
        const int lB  = s + 48;
        const int lenA = bxA ? len1 : len0;
        const bool vB = (s < 160);
        const bf16x8 z = (bf16x8)(bf16_t)0.f;
        bf16x8 a0 = z, a1 = z, a2 = z, a3 = z;
        bf16x8 c0 = z, c1 = z, c2 = z, c3 = z;
        if (lA < lenA) {
            const bf16_t* src = tb + (long)history[(long)(b0 + bxA) * NL + lA] * ND + p * 32;
            a0 = *(const bf16x8*)(src);
            a1 = *(const bf16x8*)(src + 8);
            a2 = *(const bf16x8*)(src + 16);
            a3 = *(const bf16x8*)(src + 24);
        }
        if (vB && lB < len1) {
            const bf16_t* src = tb + (long)history[(long)(b0 + 1) * NL + lB] * ND + p * 32;
            c0 = *(const bf16x8*)(src);
            c1 = *(const bf16x8*)(src + 8);
            c2 = *(const bf16x8*)(src + 16);
            c3 = *(const bf16x8*)(src + 24);
        }
        {
            bf16_t* d = &histA[bxA][lA * 64];
            const int S = (lA & 7) << 3;
            *(bf16x8*)&d[(p * 32 +  0) ^ S] = a0;
            *(bf16x8*)&d[(p * 32 +  8) ^ S] = a1;
            *(bf16x8*)&d[(p * 32 + 16) ^ S] = a2;
            *(bf16x8*)&d[(p * 32 + 24) ^ S] = a3;
        }
        if (vB) {
            bf16_t* d = &histA[1][lB * 64];
            const int S = (lB & 7) << 3;
            *(bf16x8*)&d[(p * 32 +  0) ^ S] = c0;
            *(bf16x8*)&d[(p * 32 +  8) ^ S] = c1;
            *(bf16x8*)&d[(p * 32 + 16) ^ S] = c2;
            *(bf16x8*)&d[(p * 32 + 24) ^ S] = c3;
        }
    }

    // ---- phase 2: Wb^T for BOTH rows from one pass over aW1 ----
    {
        const int n  = tid & 63;
        const int kp = tid >> 6;      // 0..7 -> k = kp*8 + i
        const long t0 = (long)item_ids[b0] * ND;
        const long t1 = (long)item_ids[b0 + 1] * ND;
        f32x4 tk0a = *(const f32x4*)(emb + t0 + kp * 8);
        f32x4 tk0b = *(const f32x4*)(emb + t0 + kp * 8 + 4);
        f32x4 tk1a = *(const f32x4*)(emb + t1 + kp * 8);
        f32x4 tk1b = *(const f32x4*)(emb + t1 + kp * 8 + 4);
        float cs0 = 0.f, cs1 = 0.f;
        bf16x8 w0v, w1v;
#pragma unroll
        for (int i = 0; i < 8; ++i) {
            int k = kp * 8 + i;
            float tk0 = (i < 4) ? tk0a[i] : tk0b[i - 4];
            float tk1 = (i < 4) ? tk1a[i] : tk1b[i - 4];
            float ah = aW1[k * 64 + n];
            float am = aW1[(64 + k) * 64 + n];
            float ap = aW1[(128 + k) * 64 + n];
            w0v[i] = (bf16_t)(ah + tk0 * ap);
            w1v[i] = (bf16_t)(ah + tk1 * ap);
            cs0 += tk0 * am;
            cs1 += tk1 * am;
        }
        const int S = (n & 7) << 3;
        *(bf16x8*)&wbT[0][n * 64 + ((kp * 8) ^ S)] = w0v;
        *(bf16x8*)&wbT[1][n * 64 + ((kp * 8) ^ S)] = w1v;
        pp2[0][kp * 64 + n] = cs0;
        pp2[1][kp * 64 + n] = cs1;
    }
    __syncthreads();   // B1

    // ---- phase 3: H = hist @ Wb via MFMA; relu; dot aW2 -> scores ----
    {
        const int wave = tid >> 6;
        const int lane = tid & 63;
        const int bx   = wave & 1;    // wave's batch row
        const int col  = lane & 15;
        const int quad = lane >> 4;

        bf16x8 bfrag[4][2];
#pragma unroll
        for (int nt = 0; nt < 4; ++nt) {
            const int n = nt * 16 + col;
            const int S = (n & 7) << 3;
#pragma unroll
            for (int kb = 0; kb < 2; ++kb)
                bfrag[nt][kb] = *(const bf16x8*)&wbT[bx][n * 64 + ((kb * 32 + quad * 8) ^ S)];
        }
        float cvals[4], a2vals[4];
#pragma unroll
        for (int nt = 0; nt < 4; ++nt) {
            const int n = nt * 16 + col;
            float s = ab1[n];
#pragma unroll
            for (int kp = 0; kp < 8; ++kp) s += pp2[bx][kp * 64 + n];
            cvals[nt]  = s;
            a2vals[nt] = aW2[n];
        }

        for (int mt = (wave >> 1); mt < MT; mt += 4) {
            const int row = mt * 16 + col;
            const int S   = (row & 7) << 3;
            const bf16_t* base = &histA[bx][row * 64];
            bf16x8 af0 = *(const bf16x8*)&base[(     quad * 8) ^ S];
            bf16x8 af1 = *(const bf16x8*)&base[(32 + quad * 8) ^ S];
            float sc[4] = {0.f, 0.f, 0.f, 0.f};
#pragma unroll
            for (int nt = 0; nt < 4; ++nt) {
                f32x4 acc = {0.f, 0.f, 0.f, 0.f};
                acc = __builtin_amdgcn_mfma_f32_16x16x32_bf16(af0, bfrag[nt][0], acc, 0, 0, 0);
                acc = __builtin_amdgcn_mfma_f32_16x16x32_bf16(af1, bfrag[nt][1], acc, 0, 0, 0);
#pragma unroll
                for (int i = 0; i < 4; ++i) {
                    float h = acc[i] + cvals[nt];
                    h = h > 0.f ? h : 0.f;
                    sc[i] += h * a2vals[nt];
                }
            }
            for (int off = 1; off < 16; off <<= 1)
#pragma unroll
                for (int i = 0; i < 4; ++i)
                    sc[i] += __shfl_xor(sc[i], off, 64);
            if (col == 0) {
                f32x4 outv = {sc[0], sc[1], sc[2], sc[3]};
                *(f32x4*)&scores[bx][mt * 16 + quad * 4] = outv;
            }
        }
    }
    __syncthreads();   // B2

    // ---- phase 4: softmax over exactly L=200 (waves 0-3: b0, 4-7: b1) ----
    {
        const int bx = tid >> 8, t = tid & 255;
        float s = (t < NL) ? scores[bx][t] : -1e30f;
        float m = s;
        for (int off = 32; off > 0; off >>= 1) m = fmaxf(m, __shfl_xor(m, off, 64));
        if ((t & 63) == 0) red[bx][t >> 6] = m;
        __syncthreads();   // B3
        m = fmaxf(fmaxf(red[bx][0], red[bx][1]), fmaxf(red[bx][2], red[bx][3]));
        float e = (t < NL) ? __expf(s - m) : 0.f;
        if (t < NL) wts[bx][t] = e;                 // unnormalized
        float ss = e;
        for (int off = 32; off > 0; off >>= 1) ss += __shfl_xor(ss, off, 64);
        if ((t & 63) == 0) red[bx][4 + (t >> 6)] = ss;
        __syncthreads();   // B4
    }

    // ---- phase 5: pooled partials = (sum_l e_l * hist_l) / tot ----
    {
        const int wave = tid >> 6, lane = tid & 63;
        const int bx = wave >> 2, q = wave & 3;
        const float rtot = 1.f / (red[bx][4] + red[bx][5] + red[bx][6] + red[bx][7]);
        float acc = 0.f;
        for (int i = 0; i < 50; ++i) {
            int l = q * 50 + i;
            acc += wts[bx][l] * (float)histA[bx][l * 64 + (lane ^ ((l & 7) << 3))];
        }
        pp2[bx][q * 64 + lane] = acc * rtot;
    }
    __syncthreads();   // B5

    // ---- phase 6: comb = [tgt, pooled, pooled - tgt] -> scores alias ----
    {
        const int bx = tid >> 8, t = tid & 255;
        if (t < 192) {
            const int d = t & 63;
            float v;
            if (t < 64) v = tgt[bx][d];
            else {
                float pl = pp2[bx][d] + pp2[bx][64 + d] + pp2[bx][128 + d] + pp2[bx][192 + d];
                v = (t < 128) ? pl : pl - tgt[bx][d];
            }
            scores[bx][t] = v;
        }
    }
    __syncthreads();   // B6

    // ---- phase 7: z1 = relu(comb @ fW1 + fb1) [192->128], both rows ----
    {
        const int cg = tid & 15;      // output j = cg*8 + jj
        const int g  = tid >> 4;      // 0..31, i in [g*6, g*6+6)
        f32x4 a00 = {0,0,0,0}, a01 = {0,0,0,0};
        f32x4 a10 = {0,0,0,0}, a11 = {0,0,0,0};
#pragma unroll
        for (int ii = 0; ii < 6; ++ii) {
            int i = g * 6 + ii;
            bf16x8 wv = *(const bf16x8*)&fW1b[i * 128 + cg * 8];
            float c0 = scores[0][i], c1 = scores[1][i];
#pragma unroll
            for (int jj = 0; jj < 4; ++jj) {
                float wA = (float)wv[jj], wB = (float)wv[4 + jj];
                a00[jj] += c0 * wA;  a01[jj] += c0 * wB;
                a10[jj] += c1 * wA;  a11[jj] += c1 * wB;
            }
        }
        *(f32x4*)&pp7[g * 256 +       cg * 8    ] = a00;
        *(f32x4*)&pp7[g * 256 +       cg * 8 + 4] = a01;
        *(f32x4*)&pp7[g * 256 + 128 + cg * 8    ] = a10;
        *(f32x4*)&pp7[g * 256 + 128 + cg * 8 + 4] = a11;
    }
    __syncthreads();   // B7
    if (tid < 256) {
        const int bx = tid >> 7, j = tid & 127;
        float s = fb1[j];
#pragma unroll
        for (int g = 0; g < 32; ++g) s += pp7[g * 256 + bx * 128 + j];
        z1[bx * 128 + j] = fmaxf(s, 0.f);
    }
    __syncthreads();   // B8

    // ---- phase 8: z2 = relu(z1 @ fW2 + fb2) [128->64], both rows ----
    {
        const int cg = tid & 7;       // output j = cg*8 + jj
        const int g  = tid >> 3;      // 0..63, i in [g*2, g*2+2)
        f32x4 a00 = {0,0,0,0}, a01 = {0,0,0,0};
        f32x4 a10 = {0,0,0,0}, a11 = {0,0,0,0};
#pragma unroll
        for (int ii = 0; ii < 2; ++ii) {
            int i = g * 2 + ii;
            bf16x8 wv = *(const bf16x8*)&fW2b[i * 64 + cg * 8];
            float v0 = z1[i], v1 = z1[128 + i];
#pragma unroll
            for (int jj = 0; jj < 4; ++jj) {
                float wA = (float)wv[jj], wB = (float)wv[4 + jj];
                a00[jj] += v0 * wA;  a01[jj] += v0 * wB;
                a10[jj] += v1 * wA;  a11[jj] += v1 * wB;
            }
        }
        *(f32x4*)&pp7[g * 128 +      cg * 8    ] = a00;
        *(f32x4*)&pp7[g * 128 +      cg * 8 + 4] = a01;
        *(f32x4*)&pp7[g * 128 + 64 + cg * 8    ] = a10;
        *(f32x4*)&pp7[g * 128 + 64 + cg * 8 + 4] = a11;
    }
    __syncthreads();   // B9
    if (tid < 128) {
        const int bx = tid >> 6, j = tid & 63;
        float s = fb2[j];
#pragma unroll
        for (int g = 0; g < 64; ++g) s += pp7[g * 128 + bx * 64 + j];
        z2[bx * 64 + j] = fmaxf(s, 0.f);
    }
    __syncthreads();   // B10

    // ---- phase 9: out = sigmoid(z2 . fW3 + fb3), wave 0 -> b0, wave 1 -> b1
    if (tid < 128) {
        const int bx = tid >> 6, j = tid & 63;
        float s = z2[bx * 64 + j] * fW3[j];
        for (int off = 32; off > 0; off >>= 1) s += __shfl_xor(s, off, 64);
        if (j == 0) out[b0 + bx] = 1.f / (1.f + __expf(-(s + fb3[0])));
    }
}

extern "C" void kernel_launch(void* const* d_in, const int* in_sizes, int n_in,
                              void* d_out, int out_size, void* d_ws, size_t ws_size,
                              hipStream_t stream) {
    const int*   item_ids = (const int*)d_in[0];
    const int*   history  = (const int*)d_in[1];
    const int*   hist_len = (const int*)d_in[2];
    const float* emb      = (const float*)d_in[3];
    const float* aW1      = (const float*)d_in[4];
    const float* ab1      = (const float*)d_in[5];
    const float* aW2      = (const float*)d_in[6];
    // d_in[7] = ab2: softmax is shift-invariant, exactly cancels -> unused
    const float* fW1      = (const float*)d_in[8];
    const float* fb1      = (const float*)d_in[9];
    const float* fW2      = (const float*)d_in[10];
    const float* fb2      = (const float*)d_in[11];
    const float* fW3      = (const float*)d_in[12];
    const float* fb3      = (const float*)d_in[13];

    // ws layout: bf16 [emb table | fW1 | fW2], contiguous
    bf16_t* tb   = (bf16_t*)d_ws;
    bf16_t* fW1b = tb + TB_ELEMS;
    bf16_t* fW2b = fW1b + FW1_ELEMS;

    cvt_kernel<<<(int)((CVT_TOTAL / 8 + 255) / 256), 256, 0, stream>>>(emb, fW1, fW2, tb);
    din_kernel1<<<NB / 2, 512, 0, stream>>>(item_ids, history, hist_len, emb, tb,
                                            aW1, ab1, aW2,
                                            fW1b, fb1, fW2b, fb2, fW3, fb3,
                                            (float*)d_out);
}

// Round 4
// 140.068 us; speedup vs baseline: 1.1675x; 1.0645x over previous
//
#include <hip/hip_runtime.h>
#include <hip/hip_bf16.h>

#define NV 100000
#define ND 64
#define NB 4096
#define NL 200
#define MT 13        // m-tiles of 16 rows -> 208 (200 real + 8 zero pad)

typedef __bf16 bf16_t;
typedef __bf16 bf16x8 __attribute__((ext_vector_type(8)));
typedef __bf16 bf16x4 __attribute__((ext_vector_type(4)));
typedef float f32x4 __attribute__((ext_vector_type(4)));

#define TB_ELEMS ((long)NV * ND)      // bf16 shadow emb table elems (12.8 MB)
#define TBV (TB_ELEMS / 8)            // 800000 vector cvt tasks
#define FT1 (128 * 192)               // fW1T elems (B-frag layout [n][k])
#define FT2 (64 * 128)                // fW2T elems
#define CVT_TASKS (TBV + FT1 + FT2)   // 832768

// ---- kernel 0: f32->bf16 emb table + transposed bf16 MLP weights ----
__global__ __launch_bounds__(256)
void cvt_kernel(const float* __restrict__ emb,
                const float* __restrict__ fW1,
                const float* __restrict__ fW2,
                bf16_t* __restrict__ tb,
                bf16_t* __restrict__ fW1T,
                bf16_t* __restrict__ fW2T)
{
    long t = (long)blockIdx.x * 256 + threadIdx.x;
    if (t >= CVT_TASKS) return;
    if (t < TBV) {
        long i = t * 8;
        f32x4 a0 = *(const f32x4*)(emb + i);
        f32x4 a1 = *(const f32x4*)(emb + i + 4);
        bf16x8 o;
#pragma unroll
        for (int j = 0; j < 4; ++j) { o[j] = (bf16_t)a0[j]; o[j + 4] = (bf16_t)a1[j]; }
        *(bf16x8*)(tb + i) = o;
    } else {
        int u = (int)(t - TBV);
        if (u < FT1) {                     // fW1T[n][k] = fW1[k][n]
            int n = u / 192, k = u - n * 192;
            fW1T[u] = (bf16_t)fW1[k * 128 + n];
        } else {                           // fW2T[n][k] = fW2[k][n]
            int u2 = u - FT1;
            int n = u2 >> 7, k = u2 & 127;
            fW2T[u2] = (bf16_t)fW2[k * 64 + n];
        }
    }
}

// Fused DIN, 2 batch rows / block (512 thr). VALU-lean version:
//  - attention scores via S^T = Wb^T @ hist^T (MFMA, both operands already
//    row-major as stored; reduce is 2 shfl over quads)
//  - pooling via ds_read_b64 vectorized VALU
//  - 3-layer MLP head via MFMA on a 16-row comb tile (rows 0-1 real),
//    weights read from pre-transposed global bf16 (prefetched to regs)
// LDS 78144 B -> 2 blocks/CU.
__global__ __launch_bounds__(512, 4)
void din_kernel1(const int* __restrict__ item_ids,
                 const int* __restrict__ history,
                 const int* __restrict__ hist_len,
                 const float* __restrict__ emb,
                 const bf16_t* __restrict__ tb,
                 const float* __restrict__ aW1,
                 const float* __restrict__ ab1,
                 const float* __restrict__ aW2,
                 const bf16_t* __restrict__ fW1T, const float* __restrict__ fb1,
                 const bf16_t* __restrict__ fW2T, const float* __restrict__ fb2,
                 const float* __restrict__ fW3, const float* __restrict__ fb3,
                 float* __restrict__ out)
{
    __shared__ __align__(16) bf16_t histA[2][208 * 64];   // 53248 B
    __shared__ __align__(16) bf16_t wbT[2][64 * 64];      // 16384 B, wbT[n][k]
    __shared__ float tgt[2][64];
    __shared__ __align__(16) float scores[2][208];
    __shared__ float wts[2][208];
    __shared__ float pp2[2][512];
    __shared__ float red[2][8];
    __shared__ float cb2[2][64];

    // MLP tiles alias wbT (dead after phase 3)
    bf16_t* comb16 = (bf16_t*)wbT;                 // [16][200] bf16, 6400 B
    bf16_t* z1s    = (bf16_t*)wbT + 3200;          // [16][136] bf16, 4352 B
    float*  z2f    = (float*)((bf16_t*)wbT + 5376); // [2][64] f32,   512 B

    const int b0  = blockIdx.x * 2;
    const int tid = threadIdx.x;
    const int len0 = hist_len[b0];
    const int len1 = hist_len[b0 + 1];

    if (tid < 128) {
        int bx = tid >> 6, d = tid & 63;
        tgt[bx][d] = emb[(long)item_ids[b0 + bx] * ND + d];
    }

    // ---- phase 1: gather 2x208 rows from bf16 table (all loads first) ----
    {
        const int p = tid & 1;        // half-row: 32 bf16 = 64 B
        const int s = tid >> 1;       // 0..255
        const int bxA = (s >= 208);
        const int lA  = s - bxA * 208;
        const int lB  = s + 48;
        const int lenA = bxA ? len1 : len0;
        const bool vB = (s < 160);
        const bf16x8 z = (bf16x8)(bf16_t)0.f;
        bf16x8 a0 = z, a1 = z, a2 = z, a3 = z;
        bf16x8 c0 = z, c1 = z, c2 = z, c3 = z;
        if (lA < lenA) {
            const bf16_t* src = tb + (long)history[(long)(b0 + bxA) * NL + lA] * ND + p * 32;
            a0 = *(const bf16x8*)(src);
            a1 = *(const bf16x8*)(src + 8);
            a2 = *(const bf16x8*)(src + 16);
            a3 = *(const bf16x8*)(src + 24);
        }
        if (vB && lB < len1) {
            const bf16_t* src = tb + (long)history[(long)(b0 + 1) * NL + lB] * ND + p * 32;
            c0 = *(const bf16x8*)(src);
            c1 = *(const bf16x8*)(src + 8);
            c2 = *(const bf16x8*)(src + 16);
            c3 = *(const bf16x8*)(src + 24);
        }
        {
            bf16_t* d = &histA[bxA][lA * 64];
            const int S = (lA & 7) << 3;
            *(bf16x8*)&d[(p * 32 +  0) ^ S] = a0;
            *(bf16x8*)&d[(p * 32 +  8) ^ S] = a1;
            *(bf16x8*)&d[(p * 32 + 16) ^ S] = a2;
            *(bf16x8*)&d[(p * 32 + 24) ^ S] = a3;
        }
        if (vB) {
            bf16_t* d = &histA[1][lB * 64];
            const int S = (lB & 7) << 3;
            *(bf16x8*)&d[(p * 32 +  0) ^ S] = c0;
            *(bf16x8*)&d[(p * 32 +  8) ^ S] = c1;
            *(bf16x8*)&d[(p * 32 + 16) ^ S] = c2;
            *(bf16x8*)&d[(p * 32 + 24) ^ S] = c3;
        }
    }

    // ---- phase 2: Wb^T for BOTH rows from one pass over aW1 ----
    {
        const int n  = tid & 63;
        const int kp = tid >> 6;      // 0..7 -> k = kp*8 + i
        const long t0 = (long)item_ids[b0] * ND;
        const long t1 = (long)item_ids[b0 + 1] * ND;
        f32x4 tk0a = *(const f32x4*)(emb + t0 + kp * 8);
        f32x4 tk0b = *(const f32x4*)(emb + t0 + kp * 8 + 4);
        f32x4 tk1a = *(const f32x4*)(emb + t1 + kp * 8);
        f32x4 tk1b = *(const f32x4*)(emb + t1 + kp * 8 + 4);
        float cs0 = 0.f, cs1 = 0.f;
        bf16x8 w0v, w1v;
#pragma unroll
        for (int i = 0; i < 8; ++i) {
            int k = kp * 8 + i;
            float tk0 = (i < 4) ? tk0a[i] : tk0b[i - 4];
            float tk1 = (i < 4) ? tk1a[i] : tk1b[i - 4];
            float ah = aW1[k * 64 + n];
            float am = aW1[(64 + k) * 64 + n];
            float ap = aW1[(128 + k) * 64 + n];
            w0v[i] = (bf16_t)(ah + tk0 * ap);
            w1v[i] = (bf16_t)(ah + tk1 * ap);
            cs0 += tk0 * am;
            cs1 += tk1 * am;
        }
        const int S = (n & 7) << 3;
        *(bf16x8*)&wbT[0][n * 64 + ((kp * 8) ^ S)] = w0v;
        *(bf16x8*)&wbT[1][n * 64 + ((kp * 8) ^ S)] = w1v;
        pp2[0][kp * 64 + n] = cs0;
        pp2[1][kp * 64 + n] = cs1;
    }
    __syncthreads();   // B1

    // cb2[bx][n] = ab1[n] + sum_k tgt_k * aW1_mid[k][n]
    if (tid < 128) {
        const int bx = tid >> 6, n = tid & 63;
        float s = ab1[n];
#pragma unroll
        for (int kp = 0; kp < 8; ++kp) s += pp2[bx][kp * 64 + n];
        cb2[bx][n] = s;
    }
    __syncthreads();   // B2

    // ---- phase 3: S^T = Wb^T @ hist^T via MFMA; relu; dot aW2 ----
    {
        const int wave = tid >> 6;
        const int lane = tid & 63;
        const int bx   = wave & 1;
        const int col  = lane & 15;
        const int quad = lane >> 4;

        // A-frags from wbT rows (n_out = nt*16+col), k-slices of d
        bf16x8 afrag[4][2];
#pragma unroll
        for (int nt = 0; nt < 4; ++nt) {
            const int n = nt * 16 + col;
            const int S = (n & 7) << 3;
#pragma unroll
            for (int kb = 0; kb < 2; ++kb)
                afrag[nt][kb] = *(const bf16x8*)&wbT[bx][n * 64 + ((kb * 32 + quad * 8) ^ S)];
        }
        // per-lane bias / aW2 for the 4 C-rows this lane owns (n_out = nt*16+quad*4+i)
        float cv[4][4], a2[4][4];
#pragma unroll
        for (int nt = 0; nt < 4; ++nt)
#pragma unroll
            for (int i = 0; i < 4; ++i) {
                const int no = nt * 16 + quad * 4 + i;
                cv[nt][i] = cb2[bx][no];
                a2[nt][i] = aW2[no];
            }

        for (int mt = (wave >> 1); mt < MT; mt += 4) {
            const int l = mt * 16 + col;     // B-operand n = l
            const int S = (l & 7) << 3;
            const bf16_t* base = &histA[bx][l * 64];
            bf16x8 bf0 = *(const bf16x8*)&base[(     quad * 8) ^ S];
            bf16x8 bf1 = *(const bf16x8*)&base[(32 + quad * 8) ^ S];
            float sc = 0.f;
#pragma unroll
            for (int nt = 0; nt < 4; ++nt) {
                f32x4 acc = {0.f, 0.f, 0.f, 0.f};
                acc = __builtin_amdgcn_mfma_f32_16x16x32_bf16(afrag[nt][0], bf0, acc, 0, 0, 0);
                acc = __builtin_amdgcn_mfma_f32_16x16x32_bf16(afrag[nt][1], bf1, acc, 0, 0, 0);
#pragma unroll
                for (int i = 0; i < 4; ++i) {
                    float h = acc[i] + cv[nt][i];
                    h = h > 0.f ? h : 0.f;
                    sc += h * a2[nt][i];
                }
            }
            // sum over the 16 C-rows = across the 4 quads
            sc += __shfl_xor(sc, 16, 64);
            sc += __shfl_xor(sc, 32, 64);
            if (quad == 0) scores[bx][mt * 16 + col] = sc;
        }
    }
    __syncthreads();   // B3

    // ---- phase 4: softmax over exactly L=200 ----
    {
        const int bx = tid >> 8, t = tid & 255;
        float s = (t < NL) ? scores[bx][t] : -1e30f;
        float m = s;
        for (int off = 32; off > 0; off >>= 1) m = fmaxf(m, __shfl_xor(m, off, 64));
        if ((t & 63) == 0) red[bx][t >> 6] = m;
        __syncthreads();   // B4
        m = fmaxf(fmaxf(red[bx][0], red[bx][1]), fmaxf(red[bx][2], red[bx][3]));
        float e = (t < NL) ? __expf(s - m) : 0.f;
        if (t < NL) wts[bx][t] = e;                 // unnormalized
        else if (t < 208) wts[bx][t] = 0.f;         // zero pad for phase 5
        float ss = e;
        for (int off = 32; off > 0; off >>= 1) ss += __shfl_xor(ss, off, 64);
        if ((t & 63) == 0) red[bx][4 + (t >> 6)] = ss;
        __syncthreads();   // B5
    }

    // ---- phase 5: pooled partials (vectorized b64 reads) ----
    {
        const int bx = tid >> 8, t = tid & 255;
        const int c = t & 15;         // d = c*4 .. c*4+3
        const int g = t >> 4;         // 0..15 row-groups
        const int w4 = (tid >> 6) & 3;
        const float rtot = 1.f / (red[bx][4] + red[bx][5] + red[bx][6] + red[bx][7]);
        f32x4 acc = {0.f, 0.f, 0.f, 0.f};
#pragma unroll
        for (int j = 0; j < 13; ++j) {
            const int l = g + j * 16;
            const float wl = wts[bx][l];
            bf16x4 v = *(const bf16x4*)&histA[bx][l * 64 + ((c * 4) ^ ((l & 7) << 3))];
#pragma unroll
            for (int k = 0; k < 4; ++k) acc[k] += wl * (float)v[k];
        }
#pragma unroll
        for (int k = 0; k < 4; ++k) {
            acc[k] += __shfl_xor(acc[k], 16, 64);
            acc[k] += __shfl_xor(acc[k], 32, 64);
            acc[k] *= rtot;
        }
        if ((tid & 63) < 16) *(f32x4*)&pp2[bx][w4 * 64 + c * 4] = acc;
    }

    // prefetch MLP weights to registers (global, L2-hot; independent of LDS)
    bf16x8 bw1[6]; float b1v;
    bf16x8 bw2[4]; float b2v = 0.f;
    {
        const int wave = tid >> 6, lane = tid & 63;
        const int col = lane & 15, quad = lane >> 4;
        const int n = wave * 16 + col;          // 0..127
#pragma unroll
        for (int ks = 0; ks < 6; ++ks)
            bw1[ks] = *(const bf16x8*)&fW1T[(long)n * 192 + ks * 32 + quad * 8];
        b1v = fb1[n];
        if (wave < 4) {
            const int n2 = wave * 16 + col;     // 0..63
#pragma unroll
            for (int ks = 0; ks < 4; ++ks)
                bw2[ks] = *(const bf16x8*)&fW2T[(long)n2 * 128 + ks * 32 + quad * 8];
            b2v = fb2[n2];
        }
    }
    __syncthreads();   // B6

    // ---- phase 6: comb16 tile (rows 0-1 = b0,b1; rows 2-15 zero) ----
    {
        const int bx = tid >> 8, t = tid & 255;
        if (t < 192) {
            const int d = t & 63;
            float v;
            if (t < 64) v = tgt[bx][d];
            else {
                float pl = pp2[bx][d] + pp2[bx][64 + d] + pp2[bx][128 + d] + pp2[bx][192 + d];
                v = (t < 128) ? pl : pl - tgt[bx][d];
            }
            comb16[bx * 200 + t] = (bf16_t)v;
        }
        if (tid >= 384) {
            const bf16x8 z = (bf16x8)(bf16_t)0.f;
            const int u = tid - 384;
#pragma unroll
            for (int s = u; s < 350; s += 128) *(bf16x8*)&comb16[400 + s * 8] = z;
        }
    }
    __syncthreads();   // B7

    // ---- phase 7: z1 = relu(comb @ fW1 + fb1) via MFMA [192->128] ----
    {
        const int wave = tid >> 6, lane = tid & 63;   // wave = nt (8 tiles)
        const int col = lane & 15, quad = lane >> 4;
        f32x4 acc = {0.f, 0.f, 0.f, 0.f};
#pragma unroll
        for (int ks = 0; ks < 6; ++ks) {
            bf16x8 a = *(const bf16x8*)&comb16[col * 200 + ks * 32 + quad * 8];
            acc = __builtin_amdgcn_mfma_f32_16x16x32_bf16(a, bw1[ks], acc, 0, 0, 0);
        }
        const int n = wave * 16 + col;
#pragma unroll
        for (int i = 0; i < 4; ++i) {
            const int m = quad * 4 + i;
            float zv = (m < 2) ? fmaxf(acc[i] + b1v, 0.f) : 0.f;
            z1s[m * 136 + n] = (bf16_t)zv;
        }
    }
    __syncthreads();   // B8

    // ---- phase 8: z2 = relu(z1 @ fW2 + fb2) via MFMA [128->64] ----
    {
        const int wave = tid >> 6, lane = tid & 63;
        const int col = lane & 15, quad = lane >> 4;
        if (wave < 4) {
            f32x4 acc = {0.f, 0.f, 0.f, 0.f};
#pragma unroll
            for (int ks = 0; ks < 4; ++ks) {
                bf16x8 a = *(const bf16x8*)&z1s[col * 136 + ks * 32 + quad * 8];
                acc = __builtin_amdgcn_mfma_f32_16x16x32_bf16(a, bw2[ks], acc, 0, 0, 0);
            }
            const int n2 = wave * 16 + col;
#pragma unroll
            for (int i = 0; i < 4; ++i) {
                const int m = quad * 4 + i;
                if (m < 2) z2f[m * 64 + n2] = fmaxf(acc[i] + b2v, 0.f);
            }
        }
    }
    __syncthreads();   // B9

    // ---- phase 9: out = sigmoid(z2 . fW3 + fb3) ----
    if (tid < 128) {
        const int bx = tid >> 6, j = tid & 63;
        float s = z2f[bx * 64 + j] * fW3[j];
        for (int off = 32; off > 0; off >>= 1) s += __shfl_xor(s, off, 64);
        if (j == 0) out[b0 + bx] = 1.f / (1.f + __expf(-(s + fb3[0])));
    }
}

extern "C" void kernel_launch(void* const* d_in, const int* in_sizes, int n_in,
                              void* d_out, int out_size, void* d_ws, size_t ws_size,
                              hipStream_t stream) {
    const int*   item_ids = (const int*)d_in[0];
    const int*   history  = (const int*)d_in[1];
    const int*   hist_len = (const int*)d_in[2];
    const float* emb      = (const float*)d_in[3];
    const float* aW1      = (const float*)d_in[4];
    const float* ab1      = (const float*)d_in[5];
    const float* aW2      = (const float*)d_in[6];
    // d_in[7] = ab2: softmax is shift-invariant, exactly cancels -> unused
    const float* fW1      = (const float*)d_in[8];
    const float* fb1      = (const float*)d_in[9];
    const float* fW2      = (const float*)d_in[10];
    const float* fb2      = (const float*)d_in[11];
    const float* fW3      = (const float*)d_in[12];
    const float* fb3      = (const float*)d_in[13];

    // ws layout: bf16 [emb table | fW1T | fW2T], contiguous, 16B-aligned
    bf16_t* tb   = (bf16_t*)d_ws;
    bf16_t* fW1T = tb + TB_ELEMS;
    bf16_t* fW2T = fW1T + FT1;

    cvt_kernel<<<(int)((CVT_TASKS + 255) / 256), 256, 0, stream>>>(emb, fW1, fW2,
                                                                   tb, fW1T, fW2T);
    din_kernel1<<<NB / 2, 512, 0, stream>>>(item_ids, history, hist_len, emb, tb,
                                            aW1, ab1, aW2,
                                            fW1T, fb1, fW2T, fb2, fW3, fb3,
                                            (float*)d_out);
}